// Round 14
// baseline (126.571 us; speedup 1.0000x reference)
//
#include <hip/hip_runtime.h>

typedef int   i32x4v __attribute__((ext_vector_type(4)));
typedef int   i32x8v __attribute__((ext_vector_type(8)));
typedef float f32x16 __attribute__((ext_vector_type(16)));

#define GLOBAL_AS(p) ((const __attribute__((address_space(1))) void*)(p))
#define LDS_AS(p)    ((__attribute__((address_space(3))) void*)(p))
#define BAR()     __builtin_amdgcn_s_barrier()
#define VMCNT(n)  asm volatile("s_waitcnt vmcnt(" #n ")" ::: "memory")
#define SP1       __builtin_amdgcn_s_setprio(1);
#define SP0       __builtin_amdgcn_s_setprio(0);

// e2m1 RTN code (values {0,.5,1,1.5,2,3,4,6}; code == bit pattern, sign=0)
__device__ inline int fp4_code(float v) {
  return (v > 0.25f) + (v > 0.75f) + (v > 1.25f) + (v > 1.75f) +
         (v > 2.5f) + (v > 3.5f) + (v > 5.0f);
}

// ---- exp(x) -> fp4 e2m1 nibble-packed [M][K/2] + E8M0 scales (packed layout) ----
// SAt packed: addr = kb*M + (m>>7)*128 + (m&31)*4 + ((m>>5)&3)
__global__ void expcvt_a4_kernel(const float* __restrict__ x,
                                 unsigned char* __restrict__ A4,
                                 unsigned char* __restrict__ SAt,
                                 int M, int K) {
  const int NKB = K >> 5;
  const int t = blockIdx.x * blockDim.x + threadIdx.x;
  const int m = t / NKB, kb = t - m * NKB;
  if (m >= M) return;
  const float4* xs4 = (const float4*)(x + (size_t)m * K + kb * 32);
  float a[32];
  float bm = -3.0e38f;
#pragma unroll
  for (int j = 0; j < 8; ++j) {
    float4 v = xs4[j];
    a[4 * j] = v.x; a[4 * j + 1] = v.y; a[4 * j + 2] = v.z; a[4 * j + 3] = v.w;
    bm = fmaxf(bm, fmaxf(fmaxf(v.x, v.y), fmaxf(v.z, v.w)));
  }
  int e = (int)ceilf(bm * 1.44269504f - 2.58496250f);
  e = min(127, max(-126, e));
  SAt[(size_t)kb * M + ((m >> 7) << 7) + ((m & 31) << 2) + ((m >> 5) & 3)] =
      (unsigned char)(e + 127);
  uint4 u;
  unsigned d[4];
#pragma unroll
  for (int g = 0; g < 4; ++g) {
    unsigned acc = 0;
#pragma unroll
    for (int j = 0; j < 8; ++j) {
      float v = exp2f(a[g * 8 + j] * 1.44269504f - (float)e);
      acc |= (unsigned)fp4_code(v) << (4 * j);
    }
    d[g] = acc;
  }
  u.x = d[0]; u.y = d[1]; u.z = d[2]; u.w = d[3];
  *(uint4*)(A4 + (size_t)m * (K >> 1) + kb * 16) = u;
}

// ---- exp(w) -> fp4, transposed Bt4[n][K/2] + packed scales ----
// SBt packed for 128-wide N blocks: addr = kb*O + (n>>7)*128 + (n&31)*4 + ((n>>5)&3)
__global__ void expcvt_wt4_kernel(const float* __restrict__ w,
                                  unsigned char* __restrict__ Bt4,
                                  unsigned char* __restrict__ SBt,
                                  int D, int O) {
  __shared__ float tile[32][33];
  int c0 = blockIdx.x * 32;   // O (col of w -> n)
  int r0 = blockIdx.y * 32;   // D (row of w -> k); one tile = one 32-K block
  int tx = threadIdx.x;       // 0..31
  int ty = threadIdx.y;       // 0..7
#pragma unroll
  for (int j = 0; j < 4; ++j) {
    int r = r0 + ty + j * 8;
    tile[ty + j * 8][tx] = __expf(w[(size_t)r * O + c0 + tx]);
  }
  __syncthreads();
  if (ty == 0) {
    const int n = c0 + tx;
    float bm = 0.0f;
#pragma unroll
    for (int d = 0; d < 32; ++d) bm = fmaxf(bm, tile[d][tx]);
    int e = (int)ceilf(__log2f(bm) - 2.58496250f);
    e = min(127, max(-126, e));
    SBt[(size_t)(r0 >> 5) * O + ((n >> 7) << 7) + ((n & 31) << 2) +
        ((n >> 5) & 3)] = (unsigned char)(e + 127);
    const float inv = exp2f(-(float)e);
    uint4 u;
    unsigned d4[4];
#pragma unroll
    for (int g = 0; g < 4; ++g) {
      unsigned acc = 0;
#pragma unroll
      for (int j = 0; j < 8; ++j)
        acc |= (unsigned)fp4_code(tile[g * 8 + j][tx] * inv) << (4 * j);
      d4[g] = acc;
    }
    u.x = d4[0]; u.y = d4[1]; u.z = d4[2]; u.w = d4[3];
    *(uint4*)(Bt4 + (size_t)n * (D >> 1) + (r0 >> 1)) = u;
  }
}

// --- 128x128 MX-fp4 GEMM: A direct-from-global (L2/L3), B via 2-buffer LDS ---
// A4 : [M][K/2] fp4 linear — per-lane fragment is 16B contiguous: row*Kb +
//      t*64 + h*32 + lk*16. Loaded global->VGPR (no LDS). h=0/h=1 share lines.
// B  : staged to LDS (8KB/step, granule-swapped + sigma_q, proven 0-conflict).
// Scales: direct global->VGPR (4 dwords/wave/iter, dbuf across x2 unroll).
// LDS = 2 x 8KB only -> block-iter LDS traffic 24KB (was 48KB).
// Ledger/wave/half-iter: 2 gload_lds(B,t+1) + 4 sload(t+1) + 4 aload(t+1,late)
// -> VMCNT(6) at next top keeps exactly {B,S}(t+1) in flight, retires the rest.

#define PAD8(f) __builtin_shufflevector(f, f, 0, 1, 2, 3, -1, -1, -1, -1)
#define MFMA4(MB, NB, AV, BV, SAv, SBv)                                      \
  acc[MB][NB] = __builtin_amdgcn_mfma_scale_f32_32x32x64_f8f6f4(             \
      AV, BV, acc[MB][NB], 4, 4, 0, SAv, 0, SBv);

#define SCALES(T, S0, S1, S2, S3)                                            \
  {                                                                          \
    const int tt = ((T) < NTK) ? (T) : NTK - 1;                              \
    S0 = *(const int*)(pSA + (size_t)(tt * 4) * M);                          \
    S1 = *(const int*)(pSA + (size_t)(tt * 4 + 2) * M);                      \
    S2 = *(const int*)(pSB + (size_t)(tt * 4) * N);                          \
    S3 = *(const int*)(pSB + (size_t)(tt * 4 + 2) * N);                      \
  }

#define AFRAGS(T)                                                            \
  {                                                                          \
    const int tt = ((T) < NTK) ? (T) : NTK - 1;                              \
    const int ko = tt << 6;                                                  \
    aF00 = *(const i32x4v*)(aB0 + ko);                                       \
    aF01 = *(const i32x4v*)(aB0 + ko + 32);                                  \
    aF10 = *(const i32x4v*)(aB1 + ko);                                       \
    aF11 = *(const i32x4v*)(aB1 + ko + 32);                                  \
  }

// COMPUTE(base, sa0,sa1,sb0,sb1): h=0 uses {aF00,aF10,sa0,sb0}, h=1 the others
#define COMPUTE(BASE, SAW0, SAW1, SBW0, SBW1)                                \
  {                                                                          \
    const char* bB = (BASE) + wc * 4096;                                     \
    {                                                                        \
      const int ch = cR0;                                                    \
      i32x4v f0 = *(const i32x4v*)(bB + l31 * 64 + ch);                      \
      i32x4v f1 = *(const i32x4v*)(bB + (32 + l31) * 64 + ch);               \
      const int sA0 = ((SAW0) >> shA) & 0xFF, sA1 = ((SAW0) >> (shA + 8)) & 0xFF; \
      const int sB0 = ((SBW0) >> shB) & 0xFF, sB1 = ((SBW0) >> (shB + 8)) & 0xFF; \
      MFMA4(0, 0, PAD8(aF00), PAD8(f0), sA0, sB0)                            \
      MFMA4(1, 0, PAD8(aF10), PAD8(f0), sA1, sB0)                            \
      MFMA4(0, 1, PAD8(aF00), PAD8(f1), sA0, sB1)                            \
      MFMA4(1, 1, PAD8(aF10), PAD8(f1), sA1, sB1)                            \
    }                                                                        \
    {                                                                        \
      const int ch = cR0 ^ 16;                                               \
      i32x4v f0 = *(const i32x4v*)(bB + l31 * 64 + ch);                      \
      i32x4v f1 = *(const i32x4v*)(bB + (32 + l31) * 64 + ch);               \
      const int sA0 = ((SAW1) >> shA) & 0xFF, sA1 = ((SAW1) >> (shA + 8)) & 0xFF; \
      const int sB0 = ((SBW1) >> shB) & 0xFF, sB1 = ((SBW1) >> (shB + 8)) & 0xFF; \
      MFMA4(0, 0, PAD8(aF01), PAD8(f0), sA0, sB0)                            \
      MFMA4(1, 0, PAD8(aF11), PAD8(f0), sA1, sB0)                            \
      MFMA4(0, 1, PAD8(aF01), PAD8(f1), sA0, sB1)                            \
      MFMA4(1, 1, PAD8(aF11), PAD8(f1), sA1, sB1)                            \
    }                                                                        \
  }

__global__ __launch_bounds__(256, 4) void gemm_mx4e_kernel(
    const unsigned char* __restrict__ A4, const unsigned char* __restrict__ Bt4,
    const unsigned char* __restrict__ SAt, const unsigned char* __restrict__ SBt,
    const float* __restrict__ bias, float* __restrict__ out,
    int M, int N, int K) {
  __shared__ char lds[16384];          // 2 x 8KB (B only)

  const int tid = threadIdx.x;
  const int wid = tid >> 6, lane = tid & 63;
  const int wr = wid >> 1, wc = wid & 1;
  const int l31 = lane & 31, lk = lane >> 5;
  const int NTK = K >> 7;              // 128-elem K-steps (16)
  const size_t Kb = (size_t)K >> 1;    // bytes per fp4 row (1024)

  // XCD-aware bijective swizzle (gridDim.x % 8 == 0 here: 2048); same-bm
  // blocks cluster per XCD -> A panel is L2-local.
  const int cpx = gridDim.x >> 3;
  const int v   = (blockIdx.x & 7) * cpx + (blockIdx.x >> 3);
  const int nbn = N >> 7;
  const int bm  = v / nbn, bn = v % nbn;
  const int brow = bm << 7, bcol = bn << 7;

  // B read swizzle (sigma_q, proven zero-conflict)
  const int swz = ((l31 & 6) << 3) ^ (l31 & 16);
  const int cR0 = (lk << 5) ^ swz;     // h=0; h=1 -> ^16

  // B staging sources (granule-swapped + inverse-swizzled; koff added per step)
  const char* gB[2];
#pragma unroll
  for (int i = 0; i < 2; ++i) {
    const int o = i * 4096 + tid * 16, row = o >> 6;
    const int sg = (((row & 6) << 3) ^ (row & 16)) >> 4;   // 2-bit granule swz
    const int gl = ((o >> 4) & 3) ^ sg;
    const int gs = ((gl & 1) << 1) | (gl >> 1);            // [lk][h] -> [h][lk]
    gB[i] = (const char*)Bt4 + (size_t)(bcol + row) * Kb + (gs << 4);
  }

  // A direct per-lane bases: row = brow + wr*64 + mb*32 + l31, +lk*16 within 64B
  const char* aB0 = (const char*)A4 + (size_t)(brow + wr * 64 + l31) * Kb + lk * 16;
  const char* aB1 = aB0 + (size_t)32 * Kb;

  // scale per-lane bases (lk folded in)
  const char* pSA = (const char*)SAt + (size_t)lk * M + brow + l31 * 4;
  const char* pSB = (const char*)SBt + (size_t)lk * N + bcol + l31 * 4;

  auto STAGE_B = [&](int t, char* base) {
    const int tt = (t < NTK) ? t : NTK - 1;    // clamp keeps ledger uniform
    const int koff = tt << 6;
#pragma unroll
    for (int i = 0; i < 2; ++i)
      __builtin_amdgcn_global_load_lds(GLOBAL_AS(gB[i] + koff),
          LDS_AS(base + i * 4096 + wid * 1024), 16, 0, 0);
  };

  f32x16 acc[2][2];
#pragma unroll
  for (int m = 0; m < 2; ++m)
#pragma unroll
    for (int n = 0; n < 2; ++n) acc[m][n] = (f32x16)0.0f;

  const int shA = wr << 4;
  const int shB = wc << 4;

  char* const L0 = lds;
  char* const L1 = lds + 8192;

  i32x4v aF00, aF01, aF10, aF11;
  int sE0, sE1, sE2, sE3, sO0, sO1, sO2, sO3;

  STAGE_B(0, L0);
  SCALES(0, sE0, sE1, sE2, sE3);
  AFRAGS(0);

  for (int j = 0; j < (NTK >> 1); ++j) {
    const int t0 = 2 * j;
    // ---- half 1: consume (L0, sE, aF@t0); prefetch t0+1 ----
    STAGE_B(t0 + 1, L1);
    SCALES(t0 + 1, sO0, sO1, sO2, sO3);
    VMCNT(6);          // keep {B,S}(t0+1) in flight; everything older retired
    BAR();
    SP1 COMPUTE(L0, sE0, sE1, sE2, sE3) SP0
    AFRAGS(t0 + 1);    // aF regs dead after the MFMAs above
    BAR();
    // ---- half 2: consume (L1, sO, aF@t0+1); prefetch t0+2 ----
    STAGE_B(t0 + 2, L0);
    SCALES(t0 + 2, sE0, sE1, sE2, sE3);
    VMCNT(6);
    BAR();
    SP1 COMPUTE(L1, sO0, sO1, sO2, sO3) SP0
    AFRAGS(t0 + 2);
    BAR();
  }

  VMCNT(0);

  // epilogue: out = log(acc) + bias, nontemporal
  // 32x32 C/D layout: col = lane&31, row = (reg&3) + 8*(reg>>2) + 4*(lane>>5)
  const int col0 = bcol + wc * 64 + l31;
  const int row0 = brow + wr * 64 + lk * 4;
  const float bv0 = bias[col0], bv1 = bias[col0 + 32];
#pragma unroll
  for (int mb = 0; mb < 2; ++mb) {
#pragma unroll
    for (int rg = 0; rg < 16; ++rg) {
      const int row = row0 + mb * 32 + (rg & 3) + 8 * (rg >> 2);
      const size_t ro = (size_t)row * N + col0;
      __builtin_nontemporal_store(__logf(acc[mb][0][rg]) + bv0, &out[ro]);
      __builtin_nontemporal_store(__logf(acc[mb][1][rg]) + bv1, &out[ro + 32]);
    }
  }
}

extern "C" void kernel_launch(void* const* d_in, const int* in_sizes, int n_in,
                              void* d_out, int out_size, void* d_ws, size_t ws_size,
                              hipStream_t stream) {
  const float* inputs = (const float*)d_in[0];
  const float* w      = (const float*)d_in[1];
  const float* bias   = (const float*)d_in[2];
  float* out = (float*)d_out;

  const int O = in_sizes[2];                 // 2048
  const int D = in_sizes[1] / O;             // 2048
  const size_t MD = (size_t)in_sizes[0];     // M*D
  const int M = (int)(MD / (size_t)D);       // 16384

  unsigned char* ws  = (unsigned char*)d_ws;
  unsigned char* A4  = ws;                                   // 16 MB
  unsigned char* Bt4 = ws + MD / 2;                          // 2 MB
  unsigned char* SAt = Bt4 + (size_t)O * D / 2;              // 1 MB
  unsigned char* SBt = SAt + MD / 32;                        // 128 KB

  const int nthr = (int)((MD / 32 + 255) / 256);
  expcvt_a4_kernel<<<nthr, 256, 0, stream>>>(inputs, A4, SAt, M, D);

  dim3 tg(O / 32, D / 32);
  expcvt_wt4_kernel<<<tg, dim3(32, 8), 0, stream>>>(w, Bt4, SBt, D, O);

  dim3 grid((M / 128) * (O / 128));
  gemm_mx4e_kernel<<<grid, 256, 0, stream>>>(A4, Bt4, SAt, SBt, bias, out,
                                             M, O, D);
}

// Round 15
// 89.558 us; speedup vs baseline: 1.4133x; 1.4133x over previous
//
#include <hip/hip_runtime.h>

typedef int   i32x4v __attribute__((ext_vector_type(4)));
typedef int   i32x8v __attribute__((ext_vector_type(8)));
typedef float f32x16 __attribute__((ext_vector_type(16)));

#define GLOBAL_AS(p) ((const __attribute__((address_space(1))) void*)(p))
#define LDS_AS(p)    ((__attribute__((address_space(3))) void*)(p))
#define BAR()     __builtin_amdgcn_s_barrier()
#define VMCNT(n)  asm volatile("s_waitcnt vmcnt(" #n ")" ::: "memory")
#define SP1       __builtin_amdgcn_s_setprio(1);
#define SP0       __builtin_amdgcn_s_setprio(0);

// e2m1 RTN code (values {0,.5,1,1.5,2,3,4,6}; code == bit pattern, sign=0)
__device__ inline int fp4_code(float v) {
  return (v > 0.25f) + (v > 0.75f) + (v > 1.25f) + (v > 1.75f) +
         (v > 2.5f) + (v > 3.5f) + (v > 5.0f);
}

// ---- exp(x) -> fp4 e2m1 nibble-packed [M][K/2] + E8M0 scales (packed layout) ----
// SAt packed: addr = kb*M + (m>>7)*128 + (m&31)*4 + ((m>>5)&3)
__global__ void expcvt_a4_kernel(const float* __restrict__ x,
                                 unsigned char* __restrict__ A4,
                                 unsigned char* __restrict__ SAt,
                                 int M, int K) {
  const int NKB = K >> 5;
  const int t = blockIdx.x * blockDim.x + threadIdx.x;
  const int m = t / NKB, kb = t - m * NKB;
  if (m >= M) return;
  const float4* xs4 = (const float4*)(x + (size_t)m * K + kb * 32);
  float a[32];
  float bm = -3.0e38f;
#pragma unroll
  for (int j = 0; j < 8; ++j) {
    float4 v = xs4[j];
    a[4 * j] = v.x; a[4 * j + 1] = v.y; a[4 * j + 2] = v.z; a[4 * j + 3] = v.w;
    bm = fmaxf(bm, fmaxf(fmaxf(v.x, v.y), fmaxf(v.z, v.w)));
  }
  int e = (int)ceilf(bm * 1.44269504f - 2.58496250f);
  e = min(127, max(-126, e));
  SAt[(size_t)kb * M + ((m >> 7) << 7) + ((m & 31) << 2) + ((m >> 5) & 3)] =
      (unsigned char)(e + 127);
  uint4 u;
  unsigned d[4];
#pragma unroll
  for (int g = 0; g < 4; ++g) {
    unsigned acc = 0;
#pragma unroll
    for (int j = 0; j < 8; ++j) {
      float v = exp2f(a[g * 8 + j] * 1.44269504f - (float)e);
      acc |= (unsigned)fp4_code(v) << (4 * j);
    }
    d[g] = acc;
  }
  u.x = d[0]; u.y = d[1]; u.z = d[2]; u.w = d[3];
  *(uint4*)(A4 + (size_t)m * (K >> 1) + kb * 16) = u;
}

// ---- exp(w) -> fp4, transposed Bt4[n][K/2] + packed scales ----
// SBt packed for 128-wide N blocks: addr = kb*O + (n>>7)*128 + (n&31)*4 + ((n>>5)&3)
__global__ void expcvt_wt4_kernel(const float* __restrict__ w,
                                  unsigned char* __restrict__ Bt4,
                                  unsigned char* __restrict__ SBt,
                                  int D, int O) {
  __shared__ float tile[32][33];
  int c0 = blockIdx.x * 32;   // O (col of w -> n)
  int r0 = blockIdx.y * 32;   // D (row of w -> k); one tile = one 32-K block
  int tx = threadIdx.x;       // 0..31
  int ty = threadIdx.y;       // 0..7
#pragma unroll
  for (int j = 0; j < 4; ++j) {
    int r = r0 + ty + j * 8;
    tile[ty + j * 8][tx] = __expf(w[(size_t)r * O + c0 + tx]);
  }
  __syncthreads();
  if (ty == 0) {
    const int n = c0 + tx;
    float bm = 0.0f;
#pragma unroll
    for (int d = 0; d < 32; ++d) bm = fmaxf(bm, tile[d][tx]);
    int e = (int)ceilf(__log2f(bm) - 2.58496250f);
    e = min(127, max(-126, e));
    SBt[(size_t)(r0 >> 5) * O + ((n >> 7) << 7) + ((n & 31) << 2) +
        ((n >> 5) & 3)] = (unsigned char)(e + 127);
    const float inv = exp2f(-(float)e);
    uint4 u;
    unsigned d4[4];
#pragma unroll
    for (int g = 0; g < 4; ++g) {
      unsigned acc = 0;
#pragma unroll
      for (int j = 0; j < 8; ++j)
        acc |= (unsigned)fp4_code(tile[g * 8 + j][tx] * inv) << (4 * j);
      d4[g] = acc;
    }
    u.x = d4[0]; u.y = d4[1]; u.z = d4[2]; u.w = d4[3];
    *(uint4*)(Bt4 + (size_t)n * (D >> 1) + (r0 >> 1)) = u;
  }
}

// --- 128x128 2-buffer MX-fp4 GEMM, 4 blocks/CU, K-step 128, log+bias epilogue ---
// r13 structure (best measured) + s_setprio around the MFMA clusters.
// 256 thr = 4 waves (2M x 2N); wave C-tile 64x64 = 2mb x 2nb of 32x32x64; acc 64
// VGPR -> ~100 regs/wave -> 4 waves/SIMD. Buffer 17408B: A 8KB @0, B 8KB @8192,
// SA 512B @16384, SB 512B @16896; x2 = 34816 -> 4 blocks/CU (16 waves).
// Double-buffer, stage distance 1 iter: per half { STAGE(t+1 -> other buf);
// VMCNT(5) retires t's loads; BAR; COMPUTE(buf t); BAR }. sigma_q swizzle
// (proven 0-conflict). Blocks free-run -> setprio has role diversity to exploit.

#define MFMA4(MB, NB, AV, BV, SAv, SBv)                                      \
  acc[MB][NB] = __builtin_amdgcn_mfma_scale_f32_32x32x64_f8f6f4(             \
      AV, BV, acc[MB][NB], 4, 4, 0, SAv, 0, SBv);

__global__ __launch_bounds__(256, 4) void gemm_mx4f_kernel(
    const unsigned char* __restrict__ A4, const unsigned char* __restrict__ Bt4,
    const unsigned char* __restrict__ SAt, const unsigned char* __restrict__ SBt,
    const float* __restrict__ bias, float* __restrict__ out,
    int M, int N, int K) {
  __shared__ char lds[34816];          // 2 x 17408

  const int tid = threadIdx.x;
  const int wid = tid >> 6, lane = tid & 63;
  const int wr = wid >> 1, wc = wid & 1;
  const int l31 = lane & 31, lk = lane >> 5;
  const int NTK = K >> 7;              // 128-elem K-steps (16)
  const size_t Kb = (size_t)K >> 1;    // bytes per fp4 row (1024)

  // XCD-aware bijective swizzle (gridDim.x % 8 == 0 here: 2048)
  const int cpx = gridDim.x >> 3;
  const int v   = (blockIdx.x & 7) * cpx + (blockIdx.x >> 3);
  const int nbn = N >> 7;
  const int bm  = v / nbn, bn = v % nbn;
  const int brow = bm << 7, bcol = bn << 7;

  // read offsets: logical granule gl = lk*2 + h at bits 4..5, XOR sigma_q(l31)
  const int swz = ((l31 & 6) << 3) ^ (l31 & 16);
  const int cR0 = (lk << 5) ^ swz;     // h=0 ; h=1 -> cR0 ^ 16

  // staging sources: granule-swapped + inverse-swizzled (koff = tt*64 added)
  const char* gA[2];
  const char* gB[2];
#pragma unroll
  for (int i = 0; i < 2; ++i) {
    const int o = i * 4096 + tid * 16, row = o >> 6;
    const int sg = (((row & 6) << 3) ^ (row & 16)) >> 4;   // 2-bit granule swz
    const int gl = ((o >> 4) & 3) ^ sg;
    const int gs = ((gl & 1) << 1) | (gl >> 1);            // [lk][h] -> [h][lk]
    gA[i] = (const char*)A4 + (size_t)(brow + row) * Kb + (gs << 4);
    gB[i] = (const char*)Bt4 + (size_t)(bcol + row) * Kb + (gs << 4);
  }
  // scale source: waves 0/1 -> SA kb {0,1}/{2,3}; waves 2/3 -> SB kb {0,1}/{2,3}
  const char* gS;
  size_t sstep;
  if (wid < 2) {
    gS = (const char*)SAt + ((size_t)(lane >> 5) + 2 * wid) * M + brow + l31 * 4;
    sstep = 4 * (size_t)M;
  } else {
    gS = (const char*)SBt + ((size_t)(lane >> 5) + 2 * (wid - 2)) * N + bcol +
         l31 * 4;
    sstep = 4 * (size_t)N;
  }

  auto STAGE = [&](int t, char* base) {
    const int tt = (t < NTK) ? t : NTK - 1;    // clamp keeps ledger uniform
    const int koff = tt << 6;
#pragma unroll
    for (int i = 0; i < 2; ++i) {
      __builtin_amdgcn_global_load_lds(GLOBAL_AS(gA[i] + koff),
          LDS_AS(base + i * 4096 + wid * 1024), 16, 0, 0);
      __builtin_amdgcn_global_load_lds(GLOBAL_AS(gB[i] + koff),
          LDS_AS(base + 8192 + i * 4096 + wid * 1024), 16, 0, 0);
    }
    __builtin_amdgcn_global_load_lds(GLOBAL_AS(gS + (size_t)tt * sstep),
        LDS_AS(base + 16384 + wid * 256 + lane * 4), 4, 0, 0);
  };

  f32x16 acc[2][2];
#pragma unroll
  for (int m = 0; m < 2; ++m)
#pragma unroll
    for (int n = 0; n < 2; ++n) acc[m][n] = (f32x16)0.0f;

  const int shA = wr << 4;     // byte (2wr+mb) -> shift shA + mb*8 (wave-uniform)
  const int shB = wc << 4;

  auto COMPUTE = [&](const char* base) {
    const char* bA = base + wr * 4096;
    const char* bB = base + 8192 + wc * 4096;
#pragma unroll
    for (int h = 0; h < 2; ++h) {
      const int ch = cR0 ^ (h << 4);
      i32x8v a8[2], b8[2];
#pragma unroll
      for (int mb = 0; mb < 2; ++mb) {
        i32x4v f = *(const i32x4v*)(bA + (mb * 32 + l31) * 64 + ch);
        a8[mb] = __builtin_shufflevector(f, f, 0, 1, 2, 3, -1, -1, -1, -1);
      }
#pragma unroll
      for (int nb = 0; nb < 2; ++nb) {
        i32x4v f = *(const i32x4v*)(bB + (nb * 32 + l31) * 64 + ch);
        b8[nb] = __builtin_shufflevector(f, f, 0, 1, 2, 3, -1, -1, -1, -1);
      }
      const int kb2 = 2 * h + lk;
      const int saw = *(const int*)(base + 16384 + kb2 * 128 + l31 * 4);
      const int sbw = *(const int*)(base + 16896 + kb2 * 128 + l31 * 4);
      const int sA0 = (saw >> shA) & 0xFF, sA1 = (saw >> (shA + 8)) & 0xFF;
      const int sB0 = (sbw >> shB) & 0xFF, sB1 = (sbw >> (shB + 8)) & 0xFF;
      SP1
      MFMA4(0, 0, a8[0], b8[0], sA0, sB0)
      MFMA4(1, 0, a8[1], b8[0], sA1, sB0)
      MFMA4(0, 1, a8[0], b8[1], sA0, sB1)
      MFMA4(1, 1, a8[1], b8[1], sA1, sB1)
      SP0
    }
  };

  char* const L0 = lds;
  char* const L1 = lds + 17408;

  STAGE(0, L0);

  for (int j = 0; j < (NTK >> 1); ++j) {
    // t = 2j: consume L0, stage t+1 -> L1
    STAGE(2 * j + 1, L1);
    VMCNT(5);          // retire t's 5 loads (issued a full iter ago)
    BAR();
    COMPUTE(L0);
    BAR();             // all waves done reading L0 before next STAGE overwrites
    // t = 2j+1: consume L1, stage t+2 -> L0
    STAGE(2 * j + 2, L0);
    VMCNT(5);
    BAR();
    COMPUTE(L1);
    BAR();
  }

  VMCNT(0);

  // epilogue: out = log(acc) + bias, nontemporal
  // 32x32 C/D layout: col = lane&31, row = (reg&3) + 8*(reg>>2) + 4*(lane>>5)
  const int col0 = bcol + wc * 64 + l31;
  const int row0 = brow + wr * 64 + lk * 4;
  const float bv0 = bias[col0], bv1 = bias[col0 + 32];
#pragma unroll
  for (int mb = 0; mb < 2; ++mb) {
#pragma unroll
    for (int rg = 0; rg < 16; ++rg) {
      const int row = row0 + mb * 32 + (rg & 3) + 8 * (rg >> 2);
      const size_t ro = (size_t)row * N + col0;
      __builtin_nontemporal_store(__logf(acc[mb][0][rg]) + bv0, &out[ro]);
      __builtin_nontemporal_store(__logf(acc[mb][1][rg]) + bv1, &out[ro + 32]);
    }
  }
}

extern "C" void kernel_launch(void* const* d_in, const int* in_sizes, int n_in,
                              void* d_out, int out_size, void* d_ws, size_t ws_size,
                              hipStream_t stream) {
  const float* inputs = (const float*)d_in[0];
  const float* w      = (const float*)d_in[1];
  const float* bias   = (const float*)d_in[2];
  float* out = (float*)d_out;

  const int O = in_sizes[2];                 // 2048
  const int D = in_sizes[1] / O;             // 2048
  const size_t MD = (size_t)in_sizes[0];     // M*D
  const int M = (int)(MD / (size_t)D);       // 16384

  unsigned char* ws  = (unsigned char*)d_ws;
  unsigned char* A4  = ws;                                   // 16 MB
  unsigned char* Bt4 = ws + MD / 2;                          // 2 MB
  unsigned char* SAt = Bt4 + (size_t)O * D / 2;              // 1 MB
  unsigned char* SBt = SAt + MD / 32;                        // 128 KB

  const int nthr = (int)((MD / 32 + 255) / 256);
  expcvt_a4_kernel<<<nthr, 256, 0, stream>>>(inputs, A4, SAt, M, D);

  dim3 tg(O / 32, D / 32);
  expcvt_wt4_kernel<<<tg, dim3(32, 8), 0, stream>>>(w, Bt4, SBt, D, O);

  dim3 grid((M / 128) * (O / 128));
  gemm_mx4f_kernel<<<grid, 256, 0, stream>>>(A4, Bt4, SAt, SBt, bias, out,
                                             M, O, D);
}